// Round 1
// baseline (131.196 us; speedup 1.0000x reference)
//
#include <hip/hip_runtime.h>

typedef __bf16 bf16x8 __attribute__((ext_vector_type(8)));
typedef float f32x4 __attribute__((ext_vector_type(4)));
typedef unsigned int u32x4 __attribute__((ext_vector_type(4)));

__device__ __forceinline__ unsigned short f2bf(float f) {
  unsigned u = __builtin_bit_cast(unsigned, f);
  u += 0x7FFFu + ((u >> 16) & 1u);
  return (unsigned short)(u >> 16);
}

// ---------------- transpose + fp32->bf16 convert (+ optional row mask) -------------
// in: [batch][R][C] f32  ->  out: [batch][C][R] bf16(ushort)
// mask (if non-null): mask[b*R + r] |= (any in[b][r][*] != 0)
__global__ void transpose_cvt(const float* __restrict__ in, unsigned short* __restrict__ out,
                              int R, int C, int* __restrict__ mask) {
  __shared__ float tile[32][33];
  __shared__ int rowAny[32];
  const int b = blockIdx.z;
  const float* inb = in + (size_t)b * R * C;
  unsigned short* outb = out + (size_t)b * R * C;
  const int r0 = blockIdx.x * 32, c0 = blockIdx.y * 32;
  const int tx = threadIdx.x, ty = threadIdx.y;
  if (ty == 0) rowAny[tx] = 0;
  __syncthreads();
#pragma unroll
  for (int i = 0; i < 4; ++i) {
    const int rr = ty + i * 8;
    float v = inb[(size_t)(r0 + rr) * C + c0 + tx];
    tile[rr][tx] = v;
    if (v != 0.0f) rowAny[rr] = 1;  // benign race: all writers store 1
  }
  __syncthreads();
#pragma unroll
  for (int i = 0; i < 4; ++i) {
    const int cc = ty + i * 8;
    outb[(size_t)(c0 + cc) * R + r0 + tx] = f2bf(tile[tx][cc]);
  }
  if (mask != nullptr && ty == 0) {
    if (rowAny[tx]) atomicOr(mask + (size_t)b * R + r0 + tx, 1);
  }
}

// ---------------- GEMM1: t[b] = a[b] (fp32, cvt on the fly) @ x[b] -----------------
// Block tile 64(M) x 512(N=full F), BK=64, 8 waves (wave tile 64x64).
// A staged in dbuf XOR-swizzled LDS (16KB); B frags loaded straight from xT (L2).
__global__ __launch_bounds__(512, 2) void gemm1(const float* __restrict__ a,
                                                const unsigned short* __restrict__ xT,
                                                unsigned short* __restrict__ tout) {
  __shared__ __align__(16) char Abuf[2][64 * 64 * 2];
  const int bid = blockIdx.x;
  const int b = bid & 7, mt = bid >> 3;   // bid%8 = batch -> per-XCD batch pinning
  const int m0 = mt * 64;
  const float* ab = a + (size_t)b * 2048 * 2048 + (size_t)m0 * 2048;
  const unsigned short* xb = xT + (size_t)b * 512 * 2048;
  unsigned short* tb = tout + ((size_t)b * 2048 + m0) * 512;

  const int tid = threadIdx.x;
  const int lane = tid & 63, w = tid >> 6;
  const int r = lane & 15, hi = lane >> 4;

  // A staging: thread loads 8 consecutive fp32 of one row
  const int arow = tid >> 3, acolw = (tid & 7);
  const float* ap = ab + (size_t)arow * 2048 + acolw * 8;
  const int awoff = (arow * 128 + acolw * 16) ^ ((arow & 7) << 4);

  // A fragment LDS byte offsets (row = mi*16 + r, k-octet = kk*32 + hi*8)
  int aoff[4][2];
#pragma unroll
  for (int mi = 0; mi < 4; ++mi)
#pragma unroll
    for (int kk = 0; kk < 2; ++kk)
      aoff[mi][kk] = (((mi * 16 + r) * 128) + kk * 64 + hi * 16) ^ ((r & 7) << 4);

  // B fragment base pointers: xT[n][k], n = w*64 + ni*16 + r, k-octet = hi*8
  const unsigned short* bp[4];
#pragma unroll
  for (int ni = 0; ni < 4; ++ni)
    bp[ni] = xb + (size_t)(w * 64 + ni * 16 + r) * 2048 + hi * 8;

  f32x4 acc[4][4] = {};

  // prologue: B frags for k0 = 0
  bf16x8 bc[4][2];
#pragma unroll
  for (int ni = 0; ni < 4; ++ni)
#pragma unroll
    for (int kk = 0; kk < 2; ++kk)
      bc[ni][kk] = *(const bf16x8*)(bp[ni] + kk * 32);

  // stage A tile 0
  {
    f32x4 p0 = *(const f32x4*)ap;
    f32x4 p1 = *(const f32x4*)(ap + 4);
    u32x4 pk;
    pk[0] = (unsigned)f2bf(p0[0]) | ((unsigned)f2bf(p0[1]) << 16);
    pk[1] = (unsigned)f2bf(p0[2]) | ((unsigned)f2bf(p0[3]) << 16);
    pk[2] = (unsigned)f2bf(p1[0]) | ((unsigned)f2bf(p1[1]) << 16);
    pk[3] = (unsigned)f2bf(p1[2]) | ((unsigned)f2bf(p1[3]) << 16);
    *(u32x4*)(&Abuf[0][awoff]) = pk;
  }
  __syncthreads();

  int cur = 0;
  const int NT = 2048 / 64;
  for (int t = 0; t < NT; ++t) {
    const int k0n = (t + 1) * 64;
    f32x4 q0, q1;
    bf16x8 bn[4][2];
    const bool more = (t + 1 < NT);
    if (more) {
      const float* apn = ap + k0n;
      q0 = *(const f32x4*)apn;
      q1 = *(const f32x4*)(apn + 4);
#pragma unroll
      for (int ni = 0; ni < 4; ++ni)
#pragma unroll
        for (int kk = 0; kk < 2; ++kk)
          bn[ni][kk] = *(const bf16x8*)(bp[ni] + k0n + kk * 32);
    }
    bf16x8 af[4][2];
#pragma unroll
    for (int mi = 0; mi < 4; ++mi)
#pragma unroll
      for (int kk = 0; kk < 2; ++kk)
        af[mi][kk] = *(const bf16x8*)(&Abuf[cur][aoff[mi][kk]]);
#pragma unroll
    for (int kk = 0; kk < 2; ++kk)
#pragma unroll
      for (int mi = 0; mi < 4; ++mi)
#pragma unroll
        for (int ni = 0; ni < 4; ++ni)
          acc[mi][ni] = __builtin_amdgcn_mfma_f32_16x16x32_bf16(af[mi][kk], bc[ni][kk],
                                                                acc[mi][ni], 0, 0, 0);
    if (more) {
      u32x4 pk;
      pk[0] = (unsigned)f2bf(q0[0]) | ((unsigned)f2bf(q0[1]) << 16);
      pk[1] = (unsigned)f2bf(q0[2]) | ((unsigned)f2bf(q0[3]) << 16);
      pk[2] = (unsigned)f2bf(q1[0]) | ((unsigned)f2bf(q1[1]) << 16);
      pk[3] = (unsigned)f2bf(q1[2]) | ((unsigned)f2bf(q1[3]) << 16);
      *(u32x4*)(&Abuf[cur ^ 1][awoff]) = pk;
      __syncthreads();
#pragma unroll
      for (int ni = 0; ni < 4; ++ni)
#pragma unroll
        for (int kk = 0; kk < 2; ++kk)
          bc[ni][kk] = bn[ni][kk];
      cur ^= 1;
    }
  }

  // epilogue: t (bf16) write. D mapping: col = lane&15, row = (lane>>4)*4 + rr
#pragma unroll
  for (int mi = 0; mi < 4; ++mi)
#pragma unroll
    for (int ni = 0; ni < 4; ++ni) {
      const int col = w * 64 + ni * 16 + r;
#pragma unroll
      for (int rr = 0; rr < 4; ++rr) {
        const int row = mi * 16 + hi * 4 + rr;
        tb[(size_t)row * 512 + col] = f2bf(acc[mi][ni][rr]);
      }
    }
}

// ---------------- GEMM2: out = relu(t @ W) * mask ---------------------------------
// M = B*N = 16384 flattened; 64x512 block tile; zero LDS, zero barriers,
// register double-buffered contiguous 16B fragment loads for both operands.
__global__ __launch_bounds__(512, 2) void gemm2(const unsigned short* __restrict__ tin,
                                                const unsigned short* __restrict__ kT,
                                                const int* __restrict__ mask,
                                                float* __restrict__ out) {
  const int m0 = blockIdx.x * 64;
  const int tid = threadIdx.x;
  const int lane = tid & 63, w = tid >> 6;
  const int r = lane & 15, hi = lane >> 4;

  const unsigned short* tp[4];
  const unsigned short* bp[4];
#pragma unroll
  for (int mi = 0; mi < 4; ++mi)
    tp[mi] = tin + (size_t)(m0 + mi * 16 + r) * 512 + hi * 8;
#pragma unroll
  for (int ni = 0; ni < 4; ++ni)
    bp[ni] = kT + (size_t)(w * 64 + ni * 16 + r) * 512 + hi * 8;

  f32x4 acc[4][4] = {};
  bf16x8 ac[4][2], bc[4][2];
#pragma unroll
  for (int mi = 0; mi < 4; ++mi)
#pragma unroll
    for (int kk = 0; kk < 2; ++kk)
      ac[mi][kk] = *(const bf16x8*)(tp[mi] + kk * 32);
#pragma unroll
  for (int ni = 0; ni < 4; ++ni)
#pragma unroll
    for (int kk = 0; kk < 2; ++kk)
      bc[ni][kk] = *(const bf16x8*)(bp[ni] + kk * 32);

  const int NT = 512 / 64;
  for (int t = 0; t < NT; ++t) {
    const int k0n = (t + 1) * 64;
    bf16x8 an[4][2], bn[4][2];
    const bool more = (t + 1 < NT);
    if (more) {
#pragma unroll
      for (int mi = 0; mi < 4; ++mi)
#pragma unroll
        for (int kk = 0; kk < 2; ++kk)
          an[mi][kk] = *(const bf16x8*)(tp[mi] + k0n + kk * 32);
#pragma unroll
      for (int ni = 0; ni < 4; ++ni)
#pragma unroll
        for (int kk = 0; kk < 2; ++kk)
          bn[ni][kk] = *(const bf16x8*)(bp[ni] + k0n + kk * 32);
    }
#pragma unroll
    for (int kk = 0; kk < 2; ++kk)
#pragma unroll
      for (int mi = 0; mi < 4; ++mi)
#pragma unroll
        for (int ni = 0; ni < 4; ++ni)
          acc[mi][ni] = __builtin_amdgcn_mfma_f32_16x16x32_bf16(ac[mi][kk], bc[ni][kk],
                                                                acc[mi][ni], 0, 0, 0);
    if (more) {
#pragma unroll
      for (int mi = 0; mi < 4; ++mi)
#pragma unroll
        for (int kk = 0; kk < 2; ++kk)
          ac[mi][kk] = an[mi][kk];
#pragma unroll
      for (int ni = 0; ni < 4; ++ni)
#pragma unroll
        for (int kk = 0; kk < 2; ++kk)
          bc[ni][kk] = bn[ni][kk];
    }
  }

#pragma unroll
  for (int mi = 0; mi < 4; ++mi) {
    const int4 mv = *(const int4*)(mask + m0 + mi * 16 + hi * 4);
    const int mvv[4] = {mv.x, mv.y, mv.z, mv.w};
#pragma unroll
    for (int ni = 0; ni < 4; ++ni) {
      const int col = w * 64 + ni * 16 + r;
#pragma unroll
      for (int rr = 0; rr < 4; ++rr) {
        const int row = m0 + mi * 16 + hi * 4 + rr;
        float v = fmaxf(acc[mi][ni][rr], 0.0f);
        if (mvv[rr] == 0) v = 0.0f;
        out[(size_t)row * 512 + col] = v;
      }
    }
  }
}

// ---------------- launch ----------------------------------------------------------
extern "C" void kernel_launch(void* const* d_in, const int* in_sizes, int n_in,
                              void* d_out, int out_size, void* d_ws, size_t ws_size,
                              hipStream_t stream) {
  const float* x = (const float*)d_in[0];        // [8][2048][512]
  const float* a = (const float*)d_in[1];        // [8][2048][2048]
  const float* wk = (const float*)d_in[2];       // [512][512]
  float* out = (float*)d_out;                    // [8][2048][512]

  char* ws = (char*)d_ws;
  unsigned short* xT = (unsigned short*)ws;                                  // 16 MB
  unsigned short* kT = (unsigned short*)(ws + (16u << 20));                  // 0.5 MB
  unsigned short* tb = (unsigned short*)(ws + (16u << 20) + (1u << 19));     // 16 MB
  int* mask = (int*)(ws + (32u << 20) + (1u << 19));                         // 64 KB

  hipMemsetAsync(mask, 0, 8 * 2048 * sizeof(int), stream);

  // x: [b][2048][512] -> xT [b][512][2048], + row mask
  transpose_cvt<<<dim3(2048 / 32, 512 / 32, 8), dim3(32, 8), 0, stream>>>(x, xT, 2048, 512, mask);
  // W: [512][512] -> Wt [512][512]
  transpose_cvt<<<dim3(512 / 32, 512 / 32, 1), dim3(32, 8), 0, stream>>>(wk, kT, 512, 512, nullptr);

  gemm1<<<dim3(256), dim3(512), 0, stream>>>(a, xT, tb);
  gemm2<<<dim3(256), dim3(512), 0, stream>>>(tb, kT, mask, out);
}